// Round 2
// baseline (24609.512 us; speedup 1.0000x reference)
//
#include <hip/hip_runtime.h>
#include <math.h>

// ---------------------------------------------------------------------------
// Bert_BiLstm_Crf: 2-layer BiLSTM (B=64,T=512,D=768,H=384/dir) -> FC(30) -> Viterbi
// All fp32. Round 2: ws-adaptive chunked pre-activation layout (crash fix).
// ---------------------------------------------------------------------------

#define B_  64
#define T_  512
#define D_  768
#define H_  384
#define G4  1536   // 4*H
#define NTAGS 30

// ---------------- transpose w_hh [1536][384] -> wT [384][1536] --------------
__global__ void transpose_w(const float* __restrict__ in, float* __restrict__ out,
                            int R, int C) {
  __shared__ float tile[32][33];
  int cbase = blockIdx.x * 32;
  int rbase = blockIdx.y * 32;
  int tx = threadIdx.x, ty = threadIdx.y;
  #pragma unroll
  for (int i = 0; i < 32; i += 8)
    tile[ty + i][tx] = in[(size_t)(rbase + ty + i) * C + cbase + tx];
  __syncthreads();
  #pragma unroll
  for (int i = 0; i < 32; i += 8)
    out[(size_t)(cbase + ty + i) * R + rbase + tx] = tile[tx][ty + i];
}

// ------------- chunk GEMM (BMR=128): Cc[b][r][n] = A[b*T+t0+r][:] @ W[n][:]^T + b1 + b2
__global__ __launch_bounds__(256)
void sgemm128(const float* __restrict__ A, int t0,
              const float* __restrict__ W,
              const float* __restrict__ bias1, const float* __restrict__ bias2,
              float* __restrict__ Cc) {
  __shared__ float As[16][128];
  __shared__ float Bs[16][128];
  const int tid = threadIdx.x;
  const int b   = blockIdx.y;                 // batch element
  const int bn  = blockIdx.x * 128;
  const int tx  = tid & 15;
  const int ty  = tid >> 4;
  const float* Abase = A + ((size_t)b * T_ + t0) * D_;

  float acc[8][8];
  #pragma unroll
  for (int i = 0; i < 8; ++i)
    #pragma unroll
    for (int j = 0; j < 8; ++j) acc[i][j] = 0.f;

  for (int k0 = 0; k0 < D_; k0 += 16) {
    #pragma unroll
    for (int s = tid; s < 512; s += 256) {
      int r = s >> 2, k4 = (s & 3) * 4;
      float4 va = *(const float4*)(Abase + (size_t)r * D_ + k0 + k4);
      As[k4 + 0][r] = va.x; As[k4 + 1][r] = va.y;
      As[k4 + 2][r] = va.z; As[k4 + 3][r] = va.w;
      float4 vb = *(const float4*)(W + (size_t)(bn + r) * D_ + k0 + k4);
      Bs[k4 + 0][r] = vb.x; Bs[k4 + 1][r] = vb.y;
      Bs[k4 + 2][r] = vb.z; Bs[k4 + 3][r] = vb.w;
    }
    __syncthreads();
    #pragma unroll
    for (int k = 0; k < 16; ++k) {
      float a[8], bv[8];
      *(float4*)(a)      = *(const float4*)&As[k][ty * 4];
      *(float4*)(a + 4)  = *(const float4*)&As[k][64 + ty * 4];
      *(float4*)(bv)     = *(const float4*)&Bs[k][tx * 4];
      *(float4*)(bv + 4) = *(const float4*)&Bs[k][64 + tx * 4];
      #pragma unroll
      for (int i = 0; i < 8; ++i)
        #pragma unroll
        for (int j = 0; j < 8; ++j)
          acc[i][j] += a[i] * bv[j];
    }
    __syncthreads();
  }

  float4 b1l = *(const float4*)(bias1 + bn + tx * 4);
  float4 b2l = *(const float4*)(bias2 + bn + tx * 4);
  float4 b1h = *(const float4*)(bias1 + bn + 64 + tx * 4);
  float4 b2h = *(const float4*)(bias2 + bn + 64 + tx * 4);
  float4 bl = {b1l.x + b2l.x, b1l.y + b2l.y, b1l.z + b2l.z, b1l.w + b2l.w};
  float4 bh = {b1h.x + b2h.x, b1h.y + b2h.y, b1h.z + b2h.z, b1h.w + b2h.w};

  #pragma unroll
  for (int i = 0; i < 8; ++i) {
    int r = (i < 4) ? (ty * 4 + i) : (64 + ty * 4 + (i - 4));
    size_t row = (size_t)b * 128 + r;
    float4 lo = {acc[i][0] + bl.x, acc[i][1] + bl.y, acc[i][2] + bl.z, acc[i][3] + bl.w};
    float4 hi = {acc[i][4] + bh.x, acc[i][5] + bh.y, acc[i][6] + bh.z, acc[i][7] + bh.w};
    *(float4*)(Cc + row * G4 + bn + tx * 4)      = lo;
    *(float4*)(Cc + row * G4 + bn + 64 + tx * 4) = hi;
  }
}

// ------------- chunk GEMM (small BMR=32 or 16), tile BMR x 128 --------------
template<int BMR>
__global__ __launch_bounds__(256)
void sgemm_small(const float* __restrict__ A, int t0,
                 const float* __restrict__ W,
                 const float* __restrict__ bias1, const float* __restrict__ bias2,
                 float* __restrict__ Cc, int cpb /* = TC/BMR */, int TC) {
  constexpr int MR = BMR / 8;
  __shared__ float As[16][BMR];
  __shared__ float Bs[16][128];
  const int tid = threadIdx.x;
  const int my  = blockIdx.y;
  const int b   = my / cpb;
  const int r0  = (my % cpb) * BMR;
  const int bn  = blockIdx.x * 128;
  const int tx  = tid & 31;   // n
  const int ty  = tid >> 5;   // m
  const float* Abase = A + ((size_t)b * T_ + t0 + r0) * D_;

  float acc[MR][4];
  #pragma unroll
  for (int i = 0; i < MR; ++i)
    #pragma unroll
    for (int j = 0; j < 4; ++j) acc[i][j] = 0.f;

  for (int k0 = 0; k0 < D_; k0 += 16) {
    if (tid < BMR * 4) {
      int r = tid >> 2, k4 = (tid & 3) * 4;
      float4 va = *(const float4*)(Abase + (size_t)r * D_ + k0 + k4);
      As[k4 + 0][r] = va.x; As[k4 + 1][r] = va.y;
      As[k4 + 2][r] = va.z; As[k4 + 3][r] = va.w;
    }
    #pragma unroll
    for (int s = tid; s < 512; s += 256) {
      int r = s >> 2, k4 = (s & 3) * 4;
      float4 vb = *(const float4*)(W + (size_t)(bn + r) * D_ + k0 + k4);
      Bs[k4 + 0][r] = vb.x; Bs[k4 + 1][r] = vb.y;
      Bs[k4 + 2][r] = vb.z; Bs[k4 + 3][r] = vb.w;
    }
    __syncthreads();
    #pragma unroll
    for (int k = 0; k < 16; ++k) {
      float4 bv = *(const float4*)&Bs[k][tx * 4];
      float a[MR];
      #pragma unroll
      for (int i = 0; i < MR; ++i) a[i] = As[k][ty * MR + i];
      #pragma unroll
      for (int i = 0; i < MR; ++i) {
        acc[i][0] += a[i] * bv.x; acc[i][1] += a[i] * bv.y;
        acc[i][2] += a[i] * bv.z; acc[i][3] += a[i] * bv.w;
      }
    }
    __syncthreads();
  }

  float4 b1v = *(const float4*)(bias1 + bn + tx * 4);
  float4 b2v = *(const float4*)(bias2 + bn + tx * 4);
  float4 bb = {b1v.x + b2v.x, b1v.y + b2v.y, b1v.z + b2v.z, b1v.w + b2v.w};
  #pragma unroll
  for (int i = 0; i < MR; ++i) {
    size_t row = (size_t)b * TC + r0 + ty * MR + i;
    float4 o = {acc[i][0] + bb.x, acc[i][1] + bb.y, acc[i][2] + bb.z, acc[i][3] + bb.w};
    *(float4*)(Cc + row * G4 + bn + tx * 4) = o;
  }
}

// ---------------- LSTM recurrence (chunked), batch-2 per WG -----------------
__device__ __forceinline__ float sigm(float x) { return 1.f / (1.f + expf(-x)); }

template<bool DO_FC>
__global__ __launch_bounds__(384)
void lstm_rec(const float* __restrict__ preF, const float* __restrict__ preB,
              const float* __restrict__ wT_f, const float* __restrict__ wT_b,
              float* __restrict__ hout,
              float* __restrict__ featsF, float* __restrict__ featsB,
              const float* __restrict__ fc_w,
              float* __restrict__ stateH, float* __restrict__ stateC,
              int c, int TC) {
  const int bid  = blockIdx.x;          // 0..63
  const int dir  = bid & 1;
  const int pair = bid >> 1;
  const int b0 = pair * 2, b1 = b0 + 1;
  const float* __restrict__ pre = dir ? preB : preF;
  const float* __restrict__ wT  = dir ? wT_b : wT_f;
  const int hoff = dir ? H_ : 0;

  const int tid = threadIdx.x;          // 0..383
  const int g   = tid / 96;
  const int q   = tid % 96;
  const int ncol = g * H_ + q * 4;

  __shared__ float hA[H_], hB[H_];
  __shared__ float gA[G4], gB[G4];
  __shared__ float fcw[NTAGS * 385];    // padded stride 385 (bank-conflict-free)
  __shared__ float fpart[360];

  float c0, c1;
  const int sBase0 = (dir * B_ + b0) * H_ + tid;
  const int sBase1 = (dir * B_ + b1) * H_ + tid;
  if (c == 0) {
    hA[tid] = 0.f; hB[tid] = 0.f; c0 = 0.f; c1 = 0.f;
  } else {
    hA[tid] = stateH[sBase0]; hB[tid] = stateH[sBase1];
    c0 = stateC[sBase0];      c1 = stateC[sBase1];
  }
  if constexpr (DO_FC) {
    for (int i = tid; i < NTAGS * H_; i += 384) {
      int n = i / H_, k = i - n * H_;
      fcw[n * 385 + k] = fc_w[(size_t)n * D_ + hoff + k];
    }
  }
  __syncthreads();

  for (int step = 0; step < TC; ++step) {
    const int t  = dir ? (T_ - 1 - c * TC - step) : (c * TC + step);
    const int lt = dir ? (TC - 1 - step) : step;

    float4 a0 = {0.f, 0.f, 0.f, 0.f};
    float4 a1 = {0.f, 0.f, 0.f, 0.f};
    const float* wp = wT + ncol;
    #pragma unroll 4
    for (int k = 0; k < H_; ++k) {
      float4 w = *(const float4*)(wp);
      wp += G4;
      float h0k = hA[k], h1k = hB[k];
      a0.x += h0k * w.x; a0.y += h0k * w.y; a0.z += h0k * w.z; a0.w += h0k * w.w;
      a1.x += h1k * w.x; a1.y += h1k * w.y; a1.z += h1k * w.z; a1.w += h1k * w.w;
    }
    {
      const float4 p0 = *(const float4*)(pre + ((size_t)b0 * TC + lt) * G4 + ncol);
      const float4 p1 = *(const float4*)(pre + ((size_t)b1 * TC + lt) * G4 + ncol);
      a0.x += p0.x; a0.y += p0.y; a0.z += p0.z; a0.w += p0.w;
      a1.x += p1.x; a1.y += p1.y; a1.z += p1.z; a1.w += p1.w;
    }
    *(float4*)&gA[ncol] = a0;
    *(float4*)&gB[ncol] = a1;
    __syncthreads();

    // gate phase: thread tid owns hidden unit tid
    {
      float i0 = sigm(gA[tid]);
      float f0 = sigm(gA[H_ + tid]);
      float g0 = tanhf(gA[2 * H_ + tid]);
      float o0 = sigm(gA[3 * H_ + tid]);
      c0 = f0 * c0 + i0 * g0;
      float h0n = o0 * tanhf(c0);

      float i1 = sigm(gB[tid]);
      float f1 = sigm(gB[H_ + tid]);
      float g1 = tanhf(gB[2 * H_ + tid]);
      float o1 = sigm(gB[3 * H_ + tid]);
      c1 = f1 * c1 + i1 * g1;
      float h1n = o1 * tanhf(c1);

      if constexpr (!DO_FC) {
        hout[((size_t)b0 * T_ + t) * (2 * H_) + hoff + tid] = h0n;
        hout[((size_t)b1 * T_ + t) * (2 * H_) + hoff + tid] = h1n;
      }
      hA[tid] = h0n;
      hB[tid] = h1n;
    }
    __syncthreads();

    if constexpr (DO_FC) {
      if (tid < 360) {
        int n = tid / 12, s = tid % 12;
        int bb = s / 6, sl = s % 6;
        const float* hs = bb ? hB : hA;
        const float* wrow = &fcw[n * 385 + sl * 64];
        const float* hp = hs + sl * 64;
        float acc = 0.f;
        #pragma unroll
        for (int j = 0; j < 64; j += 4)
          acc += hp[j] * wrow[j] + hp[j + 1] * wrow[j + 1]
               + hp[j + 2] * wrow[j + 2] + hp[j + 3] * wrow[j + 3];
        fpart[tid] = acc;
      }
      __syncthreads();
      if (tid < 60) {
        int n = tid >> 1, bb = tid & 1;
        const float* fp = &fpart[n * 12 + bb * 6];
        float sum = ((fp[0] + fp[1]) + (fp[2] + fp[3])) + (fp[4] + fp[5]);
        float* fo = dir ? featsB : featsF;
        fo[((size_t)(bb ? b1 : b0) * T_ + t) * NTAGS + n] = sum;
      }
      // no extra barrier needed: next write to fpart/hA happens after 2 barriers
    }
  }

  stateH[sBase0] = hA[tid]; stateH[sBase1] = hB[tid];
  stateC[sBase0] = c0;      stateC[sBase1] = c1;
}

// ---------------- Viterbi: one wave per batch element -----------------------
__global__ __launch_bounds__(64)
void viterbi_kernel(const float* __restrict__ featsF, const float* __restrict__ featsB,
                    const float* __restrict__ fc_b,
                    const float* __restrict__ trans,
                    float* __restrict__ score_out, float* __restrict__ path_out) {
  const int b = blockIdx.x;
  const int lane = threadIdx.x;
  __shared__ float trs[NTAGS * NTAGS];
  __shared__ float fcb[NTAGS];
  __shared__ float ld[32];
  __shared__ unsigned char psi[T_ - 1][NTAGS];

  for (int i = lane; i < NTAGS * NTAGS; i += 64) trs[i] = trans[i];
  if (lane < NTAGS) { fcb[lane] = fc_b[lane]; ld[lane] = -10000.0f; }
  __syncthreads();

  for (int t = 1; t < T_; ++t) {
    float best = -INFINITY; int arg = 0;
    if (lane < NTAGS) {
      #pragma unroll
      for (int p = 0; p < NTAGS; ++p) {
        float v = trs[lane * NTAGS + p] + ld[p];
        if (v > best) { best = v; arg = p; }   // strict > : first-occurrence argmax
      }
    }
    __syncthreads();
    if (lane < NTAGS) {
      size_t idx = ((size_t)b * T_ + t) * NTAGS + lane;
      ld[lane] = best + featsF[idx] + featsB[idx] + fcb[lane];
      psi[t - 1][lane] = (unsigned char)arg;
    }
    __syncthreads();
  }

  if (lane == 0) {
    float best = ld[0]; int last = 0;
    #pragma unroll
    for (int p = 1; p < NTAGS; ++p)
      if (ld[p] > best) { best = ld[p]; last = p; }
    score_out[b] = best;
    int tag = last;
    path_out[(size_t)b * T_ + (T_ - 1)] = (float)tag;
    for (int t = T_ - 2; t >= 0; --t) {
      tag = psi[t][tag];
      path_out[(size_t)b * T_ + t] = (float)tag;
    }
  }
}

// ---------------------------------------------------------------------------
extern "C" void kernel_launch(void* const* d_in, const int* in_sizes, int n_in,
                              void* d_out, int out_size, void* d_ws, size_t ws_size,
                              hipStream_t stream) {
  const float* embeds = (const float*)d_in[0];
  const float* trans  = (const float*)d_in[1];
  const float* fc_w   = (const float*)d_in[2];
  const float* fc_b   = (const float*)d_in[3];
  const float* w_ih[2][2] = {{(const float*)d_in[4],  (const float*)d_in[8]},
                             {(const float*)d_in[12], (const float*)d_in[16]}};
  const float* w_hh[2][2] = {{(const float*)d_in[5],  (const float*)d_in[9]},
                             {(const float*)d_in[13], (const float*)d_in[17]}};
  const float* b_ih[2][2] = {{(const float*)d_in[6],  (const float*)d_in[10]},
                             {(const float*)d_in[14], (const float*)d_in[18]}};
  const float* b_hh[2][2] = {{(const float*)d_in[7],  (const float*)d_in[11]},
                             {(const float*)d_in[15], (const float*)d_in[19]}};

  const size_t HB = (size_t)B_ * T_ * (2 * H_);   // 25,165,824 floats (h1)
  const size_t WT = (size_t)H_ * G4;              // 589,824 floats
  const size_t FT = (size_t)B_ * T_ * NTAGS;      // 983,040 floats
  const size_t ST = (size_t)2 * B_ * H_;          // 49,152 floats

  // choose time-chunk TC so everything fits ws_size
  const size_t fixed_bytes = (HB + 4 * WT + 2 * FT + 2 * ST) * 4;
  int TC = 16;
  if (ws_size >= fixed_bytes + 2ull * B_ * 128 * G4 * 4) TC = 128;
  else if (ws_size >= fixed_bytes + 2ull * B_ * 32 * G4 * 4) TC = 32;
  const size_t PRE = (size_t)B_ * TC * G4;

  float* ws = (float*)d_ws;
  float* hbuf   = ws;
  float* preF   = hbuf + HB;
  float* preB   = preF + PRE;
  float* wt[2][2];
  wt[0][0] = preB + PRE;
  wt[0][1] = wt[0][0] + WT;
  wt[1][0] = wt[0][1] + WT;
  wt[1][1] = wt[1][0] + WT;
  float* featsF = wt[1][1] + WT;
  float* featsB = featsF + FT;
  float* stH    = featsB + FT;
  float* stC    = stH + ST;

  // 1) transpose the four W_hh matrices
  {
    dim3 tb(32, 8), tg(H_ / 32, G4 / 32);
    for (int l = 0; l < 2; ++l)
      for (int d = 0; d < 2; ++d)
        transpose_w<<<tg, tb, 0, stream>>>(w_hh[l][d], wt[l][d], G4, H_);
  }

  const int nch = T_ / TC;
  for (int layer = 0; layer < 2; ++layer) {
    const float* A = (layer == 0) ? embeds : hbuf;
    for (int c = 0; c < nch; ++c) {
      const int t0f = c * TC;
      const int t0b = T_ - (c + 1) * TC;
      if (TC == 128) {
        dim3 gg(G4 / 128, B_);
        sgemm128<<<gg, 256, 0, stream>>>(A, t0f, w_ih[layer][0], b_ih[layer][0], b_hh[layer][0], preF);
        sgemm128<<<gg, 256, 0, stream>>>(A, t0b, w_ih[layer][1], b_ih[layer][1], b_hh[layer][1], preB);
      } else if (TC == 32) {
        dim3 gg(G4 / 128, B_);
        sgemm_small<32><<<gg, 256, 0, stream>>>(A, t0f, w_ih[layer][0], b_ih[layer][0], b_hh[layer][0], preF, 1, TC);
        sgemm_small<32><<<gg, 256, 0, stream>>>(A, t0b, w_ih[layer][1], b_ih[layer][1], b_hh[layer][1], preB, 1, TC);
      } else {
        dim3 gg(G4 / 128, B_);
        sgemm_small<16><<<gg, 256, 0, stream>>>(A, t0f, w_ih[layer][0], b_ih[layer][0], b_hh[layer][0], preF, 1, TC);
        sgemm_small<16><<<gg, 256, 0, stream>>>(A, t0b, w_ih[layer][1], b_ih[layer][1], b_hh[layer][1], preB, 1, TC);
      }
      if (layer == 0) {
        lstm_rec<false><<<64, 384, 0, stream>>>(preF, preB, wt[0][0], wt[0][1], hbuf,
                                                nullptr, nullptr, nullptr, stH, stC, c, TC);
      } else {
        lstm_rec<true><<<64, 384, 0, stream>>>(preF, preB, wt[1][0], wt[1][1], nullptr,
                                               featsF, featsB, fc_w, stH, stC, c, TC);
      }
    }
  }

  // Viterbi -> d_out = [score(64) | path(64*512) as float]
  float* score = (float*)d_out;
  float* path  = score + B_;
  viterbi_kernel<<<B_, 64, 0, stream>>>(featsF, featsB, fc_b, trans, score, path);
}